// Round 10
// baseline (604.379 us; speedup 1.0000x reference)
//
#include <hip/hip_runtime.h>
#include <hip/hip_fp16.h>

#define EPS 1e-5f
constexpr int NT = 256;
constexpr int BSH = 8;            // bucket = dst >> 8 (256 nodes per bucket; R10: halve bfill block latency)
constexpr int BNODES = 1 << BSH;
constexpr int CH = 2048;          // edges per partition block
constexpr int PADCAP = 15 * BNODES; // extra per-bucket csr capacity for pad-to-16

typedef _Float16 v8h __attribute__((ext_vector_type(8)));
typedef float v4f __attribute__((ext_vector_type(4)));

// ---------------- prepw + bucket histogram merged (verified R7-R9) ----------------

__global__ __launch_bounds__(NT) void prep_bhist_kernel(const float* __restrict__ W1, const float* __restrict__ W2,
                                                        const float* __restrict__ W3, __half* __restrict__ Wt1,
                                                        __half* __restrict__ Wt2, __half* __restrict__ Wt3,
                                                        __half* __restrict__ bufA, const int* __restrict__ dst,
                                                        int* __restrict__ gbhist, int N, int E, int NBUK) {
    constexpr int TOT = 256 * 128 + 128 * 64 + 64 * 32 + 128;
    for (int i = blockIdx.x * NT + threadIdx.x; i < TOT; i += gridDim.x * NT) {
        if (i < 256 * 128) {
            int k = i >> 7, f = i & 127;
            Wt1[f * 256 + k] = __float2half(W1[i]);
        } else if (i < 256 * 128 + 128 * 64) {
            int j = i - 256 * 128; int k = j >> 6, f = j & 63;
            Wt2[f * 128 + k] = __float2half(W2[j]);
        } else if (i < 256 * 128 + 128 * 64 + 64 * 32) {
            int j = i - 256 * 128 - 128 * 64; int k = j >> 5, f = j & 31;
            Wt3[f * 64 + k] = __float2half(W3[j]);
        } else {
            bufA[(size_t)N * 128 + (i - (256 * 128 + 128 * 64 + 64 * 32))] = __float2half(0.f);
        }
    }
    __shared__ int h[512];
    int tid = threadIdx.x;
    for (int i = tid; i < 512; i += NT) h[i] = 0;
    __syncthreads();
    for (int e = blockIdx.x * NT + tid; e < E; e += gridDim.x * NT)
        atomicAdd(&h[dst[e] >> BSH], 1);
    __syncthreads();
    for (int i = tid; i < NBUK; i += NT)
        if (h[i]) atomicAdd(&gbhist[i], h[i]);
}

// ---------------- bucket scan: bbase[0..NBUK] (exclusive), gcur = bbase ----------------

__global__ __launch_bounds__(NT) void bscan_kernel(const int* __restrict__ gbhist, int* __restrict__ bbase,
                                                   int* __restrict__ gcur, int E, int NBUK) {
    __shared__ int wsum[5];
    int tid = threadIdx.x;
    int lane = tid & 63, wid = tid >> 6;
    int e0 = (2 * tid < NBUK) ? gbhist[2 * tid] : 0;
    int e1 = (2 * tid + 1 < NBUK) ? gbhist[2 * tid + 1] : 0;
    int u = e0 + e1;
    int incl = u;
    #pragma unroll
    for (int off = 1; off < 64; off <<= 1) {
        int t = __shfl_up(incl, off, 64);
        if (lane >= off) incl += t;
    }
    if (lane == 63) wsum[wid] = incl;
    __syncthreads();
    if (tid == 0) { int s = 0; for (int w = 0; w < 4; w++) { int t = wsum[w]; wsum[w] = s; s += t; } }
    __syncthreads();
    int base = wsum[wid] + incl - u;
    if (2 * tid < NBUK)     { bbase[2 * tid] = base;          gcur[2 * tid] = base; }
    if (2 * tid + 1 < NBUK) { bbase[2 * tid + 1] = base + e0; gcur[2 * tid + 1] = base + e0; }
    if (tid == 0) bbase[NBUK] = E;
}

// ---------------- phase 1 body: partition edges into ebuf by bucket (staged, proven) ----------------
// ebuf entry: (dst & (BNODES-1)) << 18 | src   (N < 2^18, local idx fits 8 bits)

__device__ __forceinline__ void part_body(int bx, const int* __restrict__ src, const int* __restrict__ dst,
                                          int* __restrict__ gcur, int* __restrict__ ebuf,
                                          int E, int NBUK, char* smem) {
    constexpr int EPT = CH / NT;   // 8 edges per thread
    int* hist  = (int*)smem;             // 512 (>= NBUK)
    int* lscan = hist + 512;             // 512
    int* gbase = lscan + 512;            // 512
    int2* stage = (int2*)(gbase + 512);  // CH int2 = 16 KB
    int tid = threadIdx.x;
    int lane = tid & 63;
    int e0 = bx * CH;

    for (int i = tid; i < 512; i += NT) hist[i] = 0;
    __syncthreads();

    int2 ed[EPT]; int rank[EPT]; int buk[EPT];
    #pragma unroll
    for (int j = 0; j < EPT; j++) {
        int e = e0 + j * NT + tid;
        if (e < E) {
            ed[j].x = src[e]; ed[j].y = dst[e];
            buk[j] = ed[j].y >> BSH;
            rank[j] = atomicAdd(&hist[buk[j]], 1);
        } else buk[j] = -1;
    }
    __syncthreads();
    if (tid < 64) {
        int bi = tid * 8;
        int v[8]; int s = 0;
        #pragma unroll
        for (int j = 0; j < 8; j++) { v[j] = s; s += hist[bi + j]; }
        int incl = s;
        #pragma unroll
        for (int off = 1; off < 64; off <<= 1) {
            int t = __shfl_up(incl, off, 64);
            if (lane >= off) incl += t;
        }
        int lb = incl - s;
        #pragma unroll
        for (int j = 0; j < 8; j++) lscan[bi + j] = lb + v[j];
    }
    __syncthreads();
    for (int i = tid; i < NBUK; i += NT) {
        int c = hist[i];
        gbase[i] = c ? atomicAdd(&gcur[i], c) : 0;
    }
    #pragma unroll
    for (int j = 0; j < EPT; j++)
        if (buk[j] >= 0) stage[lscan[buk[j]] + rank[j]] = ed[j];
    __syncthreads();
    int cnt = min(E - e0, CH);
    for (int i = tid; i < cnt; i += NT) {
        int2 e = stage[i];
        int b = e.y >> BSH;
        ebuf[gbase[b] + (i - lscan[b])] = ((e.y & (BNODES - 1)) << 18) | e.x;
    }
}

// ---------------- phase 2 body: per-bucket row_start/pdeg/dis + padded csr fill ----------------
// NOTE: ldeg/lrs zeroed to full 512 regardless of BNODES (scan reads ldeg[2*tid+1] up to 511).

__device__ __forceinline__ void bfill_body(int bx, const int* __restrict__ ebuf, const int* __restrict__ bbase,
                                           int* __restrict__ row_start, int* __restrict__ pdeg,
                                           float* __restrict__ dis, __half* __restrict__ dis_h,
                                           int* __restrict__ csr, int N, char* smem) {
    int* ldeg = (int*)smem;      // 512
    int* lrs  = ldeg + 512;      // 512
    int* wsum = lrs + 512;       // 8
    int tid = threadIdx.x;
    int lane = tid & 63, wid = tid >> 6;
    int b = bx;
    int node0 = b << BSH;
    int nn = min(BNODES, N - node0);
    int beg = bbase[b], end = bbase[b + 1];
    int begp = beg + b * PADCAP;

    for (int i = tid; i < 512; i += NT) ldeg[i] = 0;
    __syncthreads();
    for (int i = beg + tid; i < end; i += NT)
        atomicAdd(&ldeg[ebuf[i] >> 18], 1);
    __syncthreads();
    int e0 = ldeg[2 * tid], e1 = ldeg[2 * tid + 1];
    int p0 = (e0 + 15) & ~15, p1 = (e1 + 15) & ~15;
    int u = p0 + p1;
    int incl = u;
    #pragma unroll
    for (int off = 1; off < 64; off <<= 1) {
        int t = __shfl_up(incl, off, 64);
        if (lane >= off) incl += t;
    }
    if (lane == 63) wsum[wid] = incl;
    __syncthreads();
    if (tid == 0) { int s = 0; for (int w = 0; w < 4; w++) { int t = wsum[w]; wsum[w] = s; s += t; } }
    __syncthreads();
    int base = wsum[wid] + incl - u;
    lrs[2 * tid] = base;
    lrs[2 * tid + 1] = base + p0;
    __syncthreads();
    for (int i = tid; i < nn; i += NT) {
        int dg = ldeg[i];
        pdeg[node0 + i] = (dg + 15) & ~15;
        row_start[node0 + i] = begp + lrs[i];
        float dv = rsqrtf((float)dg + 1.0f);
        dis[node0 + i] = dv;
        dis_h[node0 + i] = __float2half(dv);
    }
    if (bx == 0 && tid == 0) dis_h[N] = __float2half(0.f);
    __syncthreads();
    for (int i = tid; i < 512; i += NT) ldeg[i] = 0;   // reuse as cursor
    __syncthreads();
    for (int i = beg + tid; i < end; i += NT) {
        int code = ebuf[i];
        int l = code >> 18;
        int off = atomicAdd(&ldeg[l], 1);
        csr[begp + lrs[l] + off] = code & 0x3FFFF;
    }
    __syncthreads();
    // pad fill: sentinel N (zero row)
    for (int i = tid; i < nn; i += NT) {
        int dg = ldeg[i];
        int pd = (dg + 15) & ~15;
        int cbase = begp + lrs[i];
        for (int k = dg; k < pd; k++) csr[cbase + k] = N;
    }
}

// ---------------- MFMA GEMM body ----------------
// NORM: computes BN affine from S1/S2/g/bt inline, applies relu(v*a+c) on fp16 load.
// SC:   scales output row by dis[row]. Row N gets zeros (sentinel for padded agg).

template<int K, int F, bool NORM, bool SC>
__device__ __forceinline__ void mgemm_body(int bx, const void* __restrict__ Xv, const __half* __restrict__ Wt,
                                           const float* __restrict__ dis, const float* __restrict__ S1,
                                           const float* __restrict__ S2, const float* __restrict__ g,
                                           const float* __restrict__ bt, __half* __restrict__ out, int N,
                                           char* smem) {
    constexpr int KC = 32;
    constexpr int CG = F / 16;
    constexpr int LDA = KC + 8;
    __half* As = (__half*)smem;                      // 64*LDA
    __half* Bs = (__half*)(smem + 64 * LDA * 2);     // F*LDA
    float* as_ = (float*)(smem + 64 * LDA * 2 + F * LDA * 2);
    float* cs_ = as_ + K;

    int tid = threadIdx.x;
    if constexpr (NORM) {
        float inv = 1.0f / (float)N;
        for (int i = tid; i < K; i += NT) {
            float mu = S1[i] * inv;
            float var = fmaxf(S2[i] * inv - mu * mu, 0.f);
            float av = g[i] * rsqrtf(var + EPS);
            as_[i] = av;
            cs_[i] = bt[i] - mu * av;
        }
        __syncthreads();
    }
    int row0 = bx * 64;
    int wid = tid >> 6, lane = tid & 63;
    int quad = lane >> 4, l16 = lane & 15;
    int tr = tid >> 3;
    int tk = (tid & 7) * 4;

    v4f acc[CG];
    #pragma unroll
    for (int gg = 0; gg < CG; gg++) acc[gg] = (v4f)0.f;

    for (int k0 = 0; k0 < K; k0 += KC) {
        #pragma unroll
        for (int r = tr; r < 64; r += 32) {
            int row = row0 + r;
            __half h0, h1, h2, h3;
            if (row < N) {
                if constexpr (NORM) {
                    const __half2* xp = (const __half2*)((const __half*)Xv + (size_t)row * K + k0 + tk);
                    float2 v0 = __half22float2(xp[0]);
                    float2 v1 = __half22float2(xp[1]);
                    h0 = __float2half(fmaxf(v0.x * as_[k0 + tk]     + cs_[k0 + tk],     0.f));
                    h1 = __float2half(fmaxf(v0.y * as_[k0 + tk + 1] + cs_[k0 + tk + 1], 0.f));
                    h2 = __float2half(fmaxf(v1.x * as_[k0 + tk + 2] + cs_[k0 + tk + 2], 0.f));
                    h3 = __float2half(fmaxf(v1.y * as_[k0 + tk + 3] + cs_[k0 + tk + 3], 0.f));
                } else {
                    float4 v = *(const float4*)((const float*)Xv + (size_t)row * K + k0 + tk);
                    h0 = __float2half(v.x); h1 = __float2half(v.y);
                    h2 = __float2half(v.z); h3 = __float2half(v.w);
                }
            } else {
                h0 = h1 = h2 = h3 = __float2half(0.f);
            }
            __half2* dst = (__half2*)&As[r * LDA + tk];
            dst[0] = __halves2half2(h0, h1);
            dst[1] = __halves2half2(h2, h3);
        }
        #pragma unroll
        for (int n = tr; n < F; n += 32) {
            const __half2* wp = (const __half2*)(Wt + (size_t)n * K + k0 + tk);
            __half2* dst = (__half2*)&Bs[n * LDA + tk];
            dst[0] = wp[0];
            dst[1] = wp[1];
        }
        __syncthreads();
        v8h a = *(const v8h*)&As[(wid * 16 + l16) * LDA + quad * 8];
        #pragma unroll
        for (int gg = 0; gg < CG; gg++) {
            v8h b = *(const v8h*)&Bs[(gg * 16 + l16) * LDA + quad * 8];
            acc[gg] = __builtin_amdgcn_mfma_f32_16x16x32_f16(a, b, acc[gg], 0, 0, 0);
        }
        __syncthreads();
    }
    #pragma unroll
    for (int reg = 0; reg < 4; reg++) {
        int row = row0 + wid * 16 + quad * 4 + reg;
        if (row < N) {
            float d = SC ? dis[row] : 1.0f;
            #pragma unroll
            for (int gg = 0; gg < CG; gg++)
                out[(size_t)row * F + gg * 16 + l16] = __float2half(d * acc[gg][reg]);
        } else if (row == N) {
            #pragma unroll
            for (int gg = 0; gg < CG; gg++)
                out[(size_t)row * F + gg * 16 + l16] = __float2half(0.f);
        }
    }
}

template<int K, int F, bool NORM, bool SC>
__global__ __launch_bounds__(NT) void mgemm_kernel(const void* __restrict__ Xv, const __half* __restrict__ Wt,
                                                   const float* __restrict__ dis, const float* __restrict__ S1,
                                                   const float* __restrict__ S2, const float* __restrict__ g,
                                                   const float* __restrict__ bt, __half* __restrict__ out, int N) {
    constexpr int SMB = 64 * 40 * 2 + F * 40 * 2 + (NORM ? 8 * K : 0);
    __shared__ __align__(16) char smem[SMB];
    mgemm_body<K, F, NORM, SC>(blockIdx.x, Xv, Wt, dis, S1, S2, g, bt, out, N, smem);
}

// ---------------- fat kernels: CSR build || gemm1 ----------------

__global__ __launch_bounds__(NT) void fat1_kernel(const int* __restrict__ src, const int* __restrict__ dst,
                                                  int* __restrict__ gcur, int* __restrict__ ebuf, int E, int NBUK,
                                                  int PB, const float* __restrict__ x, const __half* __restrict__ Wt1,
                                                  __half* __restrict__ bufA, int N) {
    // part: 3*512*4 + CH*8 = 6144 + 16384 = 22528; gemm1: 15360 -> max 22528
    __shared__ __align__(16) char smem[22528];
    if ((int)blockIdx.x < PB)
        part_body(blockIdx.x, src, dst, gcur, ebuf, E, NBUK, smem);
    else
        mgemm_body<256, 128, false, false>((int)blockIdx.x - PB, x, Wt1, nullptr, nullptr, nullptr, nullptr,
                                           nullptr, bufA, N, smem);
}

__global__ __launch_bounds__(NT) void fat2_kernel(const int* __restrict__ ebuf, const int* __restrict__ bbase,
                                                  int* __restrict__ row_start, int* __restrict__ pdeg,
                                                  float* __restrict__ dis, __half* __restrict__ dis_h,
                                                  int* __restrict__ csr, const float* __restrict__ x,
                                                  const __half* __restrict__ Wt1, __half* __restrict__ bufA,
                                                  int N, int NBUK, int A) {
    __shared__ __align__(16) char smem[15872];
    if ((int)blockIdx.x < NBUK)
        bfill_body(blockIdx.x, ebuf, bbase, row_start, pdeg, dis, dis_h, csr, N, smem);
    else
        mgemm_body<256, 128, false, false>((int)blockIdx.x - NBUK + A, x, Wt1, nullptr, nullptr, nullptr, nullptr,
                                           nullptr, bufA, N, smem);
}

// ---------------- aggregation: pre[n] = fp16( dis[n]*(Σ terms) + b ) ----------------
// R4-proven: branch-free padded loop, 2-block ILP main loop, bit-identical accumulation.

template<int F, int U, bool DISW>
__global__ __launch_bounds__(NT) void agg_kernel(const __half* __restrict__ hd, const int* __restrict__ csr,
                                                 const int* __restrict__ row_start, const int* __restrict__ pdeg,
                                                 const __half* __restrict__ dis_h, const float* __restrict__ dis,
                                                 const float* __restrict__ b, __half* __restrict__ pre, int N) {
    constexpr int LR = F / 8;      // lanes per row (16 B each)
    constexpr int SUBS = 64 / LR;  // rows gathered per 16-block per wave; SUBS*U == 16
    constexpr int FSH = (F == 128) ? 7 : (F == 64) ? 6 : 5;
    int node = (blockIdx.x * NT + threadIdx.x) >> 6;
    if (node >= N) return;
    int lane = threadIdx.x & 63;
    int fl = lane % LR, sub = lane / LR;
    int beg = row_start[node];
    int nb = pdeg[node] >> 4;      // number of 16-entry blocks
    int fo = fl * 8;

    __half2 hacc[U][4];
    #pragma unroll
    for (int u = 0; u < U; u++)
        #pragma unroll
        for (int j = 0; j < 4; j++) hacc[u][j] = __half2half2(__half(0.f));

    if (sub == 0) {   // self term
        int4 v = *(const int4*)(hd + (((size_t)node << FSH) + fo));
        const __half2* hv = (const __half2*)&v;
        if constexpr (DISW) {
            __half2 dd = __half2half2(dis_h[node]);
            #pragma unroll
            for (int j = 0; j < 4; j++) hacc[0][j] = __hmul2(hv[j], dd);
        } else {
            #pragma unroll
            for (int j = 0; j < 4; j++) hacc[0][j] = hv[j];
        }
    }
    const int* cp = csr + beg + sub;
    int ib = 0;
    for (; ib + 2 <= nb; ib += 2) {
        int s[2 * U];
        #pragma unroll
        for (int u = 0; u < U; u++) {
            s[u]     = cp[u * SUBS];
            s[U + u] = cp[16 + u * SUBS];
        }
        cp += 32;
        int4 v[2 * U];
        __half dv[2 * U];
        #pragma unroll
        for (int t = 0; t < 2 * U; t++) {
            v[t] = *(const int4*)(hd + (((size_t)s[t] << FSH) + fo));
            if constexpr (DISW) dv[t] = dis_h[s[t]];
        }
        #pragma unroll
        for (int t = 0; t < 2 * U; t++) {
            const __half2* hv = (const __half2*)&v[t];
            constexpr int UM = U - 1;
            int u = t & UM;
            if constexpr (DISW) {
                __half2 dd = __half2half2(dv[t]);
                #pragma unroll
                for (int j = 0; j < 4; j++) hacc[u][j] = __hfma2(hv[j], dd, hacc[u][j]);
            } else {
                #pragma unroll
                for (int j = 0; j < 4; j++) hacc[u][j] = __hadd2(hacc[u][j], hv[j]);
            }
        }
    }
    if (ib < nb) {    // tail: one 16-block
        int s[U];
        #pragma unroll
        for (int u = 0; u < U; u++) s[u] = cp[u * SUBS];
        int4 v[U];
        __half dv[U];
        #pragma unroll
        for (int u = 0; u < U; u++) {
            v[u] = *(const int4*)(hd + (((size_t)s[u] << FSH) + fo));
            if constexpr (DISW) dv[u] = dis_h[s[u]];
        }
        #pragma unroll
        for (int u = 0; u < U; u++) {
            const __half2* hv = (const __half2*)&v[u];
            if constexpr (DISW) {
                __half2 dd = __half2half2(dv[u]);
                #pragma unroll
                for (int j = 0; j < 4; j++) hacc[u][j] = __hfma2(hv[j], dd, hacc[u][j]);
            } else {
                #pragma unroll
                for (int j = 0; j < 4; j++) hacc[u][j] = __hadd2(hacc[u][j], hv[j]);
            }
        }
    }
    // convert to f32 once, then exact cross-sub reduction
    float acc[8];
    #pragma unroll
    for (int j = 0; j < 4; j++) {
        float2 f = __half22float2(hacc[0][j]);
        acc[2 * j] = f.x; acc[2 * j + 1] = f.y;
    }
    #pragma unroll
    for (int u = 1; u < U; u++)
        #pragma unroll
        for (int j = 0; j < 4; j++) {
            float2 f = __half22float2(hacc[u][j]);
            acc[2 * j] += f.x; acc[2 * j + 1] += f.y;
        }
    #pragma unroll
    for (int m = LR; m < 64; m <<= 1)
        #pragma unroll
        for (int j = 0; j < 8; j++) acc[j] += __shfl_xor(acc[j], m, 64);
    if (sub == 0) {
        float d = dis[node];
        float4 b0 = *(const float4*)(b + fo);
        float4 b1 = *(const float4*)(b + fo + 4);
        __half2 h[4];
        h[0] = __floats2half2_rn(d * acc[0] + b0.x, d * acc[1] + b0.y);
        h[1] = __floats2half2_rn(d * acc[2] + b0.z, d * acc[3] + b0.w);
        h[2] = __floats2half2_rn(d * acc[4] + b1.x, d * acc[5] + b1.y);
        h[3] = __floats2half2_rn(d * acc[6] + b1.z, d * acc[7] + b1.w);
        *(int4*)(pre + (((size_t)node << FSH) + fo)) = *(int4*)h;
    }
}

// ---------------- BN statistics (256-block form: low atomic contention) ----------------

template<int F>
__global__ __launch_bounds__(NT) void stats_kernel(const __half* __restrict__ pre, float* __restrict__ S1,
                                                   float* __restrict__ S2, int N) {
    constexpr int FP = F / 2;
    constexpr int RPB = NT / FP;
    int tid = threadIdx.x;
    int f = tid % FP, r0 = tid / FP;
    float s1x = 0.f, s1y = 0.f, s2x = 0.f, s2y = 0.f;
    const __half2* p2 = (const __half2*)pre;
    for (int node = blockIdx.x * RPB + r0; node < N; node += gridDim.x * RPB) {
        float2 v = __half22float2(p2[(size_t)node * FP + f]);
        s1x += v.x; s1y += v.y; s2x += v.x * v.x; s2y += v.y * v.y;
    }
    __shared__ float l1x[NT], l1y[NT], l2x[NT], l2y[NT];
    l1x[tid] = s1x; l1y[tid] = s1y; l2x[tid] = s2x; l2y[tid] = s2y;
    __syncthreads();
    if (tid < FP) {
        #pragma unroll
        for (int j = 1; j < RPB; j++) {
            s1x += l1x[tid + j * FP]; s1y += l1y[tid + j * FP];
            s2x += l2x[tid + j * FP]; s2y += l2y[tid + j * FP];
        }
        atomicAdd(&S1[2 * tid], s1x); atomicAdd(&S1[2 * tid + 1], s1y);
        atomicAdd(&S2[2 * tid], s2x); atomicAdd(&S2[2 * tid + 1], s2y);
    }
}

// ---------------- final FC (BN3 params computed inline) ----------------

__global__ __launch_bounds__(NT) void fc_kernel(const __half* __restrict__ pre, const float* __restrict__ S1,
                                                const float* __restrict__ S2, const float* __restrict__ g,
                                                const float* __restrict__ bt, const float* __restrict__ wfc,
                                                const float* __restrict__ bfc, float* __restrict__ out, int N) {
    __shared__ float wa[32], wc[32], ww[32];
    int tid = threadIdx.x;
    if (tid < 32) {
        float inv = 1.0f / (float)N;
        float mu = S1[tid] * inv;
        float var = fmaxf(S2[tid] * inv - mu * mu, 0.f);
        float av = g[tid] * rsqrtf(var + EPS);
        wa[tid] = av; wc[tid] = bt[tid] - mu * av; ww[tid] = wfc[tid];
    }
    __syncthreads();
    int n = blockIdx.x * NT + tid;
    if (n >= N) return;
    const __half2* p = (const __half2*)(pre + (size_t)n * 32);
    float acc = bfc[0];
    #pragma unroll
    for (int i = 0; i < 16; i++) {
        float2 v = __half22float2(p[i]);
        int f = i * 2;
        acc += fmaxf(v.x * wa[f] + wc[f], 0.f) * ww[f];
        acc += fmaxf(v.y * wa[f + 1] + wc[f + 1], 0.f) * ww[f + 1];
    }
    out[n] = acc;
}

// ---------------- launch ----------------

extern "C" void kernel_launch(void* const* d_in, const int* in_sizes, int n_in,
                              void* d_out, int out_size, void* d_ws, size_t ws_size,
                              hipStream_t stream) {
    const float* x   = (const float*)d_in[0];
    const int*   ei  = (const int*)d_in[1];
    const float* W1  = (const float*)d_in[2];
    const float* b1  = (const float*)d_in[3];
    const float* g1  = (const float*)d_in[4];
    const float* bt1 = (const float*)d_in[5];
    const float* W2  = (const float*)d_in[6];
    const float* b2  = (const float*)d_in[7];
    const float* g2  = (const float*)d_in[8];
    const float* bt2 = (const float*)d_in[9];
    const float* W3  = (const float*)d_in[10];
    const float* b3  = (const float*)d_in[11];
    const float* g3  = (const float*)d_in[12];
    const float* bt3 = (const float*)d_in[13];
    const float* Wfc = (const float*)d_in[14];
    const float* bfc = (const float*)d_in[15];
    float* out = (float*)d_out;

    int N = in_sizes[0] / 256;
    int E = in_sizes[1] / 2;
    const int* src = ei;
    const int* dst = ei + E;
    int NBUK = (N + BNODES - 1) >> BSH;

    char* ws = (char*)d_ws;
    size_t off = 0;
    auto alloc = [&](size_t bytes) -> char* {
        char* p = ws + off;
        off += (bytes + 255) & ~(size_t)255;
        return p;
    };
    __half* bufA     = (__half*)alloc((size_t)(N + 1) * 128 * 2);   // h / hd (row N = zero sentinel)
    __half* bufB     = (__half*)alloc((size_t)N * 128 * 2);         // pre-BN aggregated
    int*   ebuf      = (int*)alloc((size_t)E * 4);
    int*   csr       = (int*)alloc(((size_t)E + (size_t)NBUK * PADCAP) * 4);
    int*   row_start = (int*)alloc((size_t)N * 4);
    int*   pdeg      = (int*)alloc((size_t)N * 4);
    float* dis       = (float*)alloc((size_t)N * 4);
    __half* dis_h    = (__half*)alloc((size_t)(N + 1) * 2);
    int*   gbhist    = (int*)alloc((size_t)NBUK * 4);
    int*   bbase     = (int*)alloc((size_t)(NBUK + 1) * 4);
    int*   gcur      = (int*)alloc((size_t)NBUK * 4);
    __half* Wt1      = (__half*)alloc(256 * 128 * 2);
    __half* Wt2      = (__half*)alloc(128 * 64 * 2);
    __half* Wt3      = (__half*)alloc(64 * 32 * 2);
    float* stats = (float*)alloc(448 * 4);
    float* S1_1 = stats;       float* S2_1 = S1_1 + 128;
    float* S1_2 = S2_1 + 128;  float* S2_2 = S1_2 + 64;
    float* S1_3 = S2_2 + 64;   float* S2_3 = S1_3 + 32;

    hipMemsetAsync(gbhist, 0, (size_t)NBUK * 4, stream);
    hipMemsetAsync(stats, 0, 448 * 4, stream);

    int GB = (N + 63) / 64;
    int PB = (E + CH - 1) / CH;
    int A = (GB * 3) / 5;           // gemm1 tiles in FAT1; rest in FAT2
    int AB = (N + 3) / 4;           // agg: one wave per node
    int NB = (N + NT - 1) / NT;

    prep_bhist_kernel<<<512, NT, 0, stream>>>(W1, W2, W3, Wt1, Wt2, Wt3, bufA, dst, gbhist, N, E, NBUK);
    bscan_kernel<<<1, NT, 0, stream>>>(gbhist, bbase, gcur, E, NBUK);
    fat1_kernel<<<PB + A, NT, 0, stream>>>(src, dst, gcur, ebuf, E, NBUK, PB, x, Wt1, bufA, N);
    fat2_kernel<<<NBUK + (GB - A), NT, 0, stream>>>(ebuf, bbase, row_start, pdeg, dis, dis_h, csr,
                                                    x, Wt1, bufA, N, NBUK, A);
    // layer 1 (hd unscaled -> DISW agg)
    agg_kernel<128, 4, true><<<AB, NT, 0, stream>>>(bufA, csr, row_start, pdeg, dis_h, dis, b1, bufB, N);
    stats_kernel<128><<<256, NT, 0, stream>>>(bufB, S1_1, S2_1, N);
    // layer 2
    mgemm_kernel<128, 64, true, true><<<GB, NT, 0, stream>>>(bufB, Wt2, dis, S1_1, S2_1, g1, bt1, bufA, N);
    agg_kernel<64, 2, false><<<AB, NT, 0, stream>>>(bufA, csr, row_start, pdeg, dis_h, dis, b2, bufB, N);
    stats_kernel<64><<<256, NT, 0, stream>>>(bufB, S1_2, S2_2, N);
    // layer 3
    mgemm_kernel<64, 32, true, true><<<GB, NT, 0, stream>>>(bufB, Wt3, dis, S1_2, S2_2, g2, bt2, bufA, N);
    agg_kernel<32, 1, false><<<AB, NT, 0, stream>>>(bufA, csr, row_start, pdeg, dis_h, dis, b3, bufB, N);
    stats_kernel<32><<<256, NT, 0, stream>>>(bufB, S1_3, S2_3, N);
    // head
    fc_kernel<<<NB, NT, 0, stream>>>(bufB, S1_3, S2_3, g3, bt3, Wfc, bfc, out, N);
}

// Round 11
// 599.816 us; speedup vs baseline: 1.0076x; 1.0076x over previous
//
#include <hip/hip_runtime.h>
#include <hip/hip_fp16.h>

#define EPS 1e-5f
constexpr int NT = 256;
constexpr int BSH = 9;            // bucket = dst >> 9 (512 nodes per bucket)
constexpr int BNODES = 1 << BSH;
constexpr int CH = 2048;          // edges per partition block
constexpr int PADCAP = 15 * BNODES; // extra per-bucket csr capacity for pad-to-16

typedef _Float16 v8h __attribute__((ext_vector_type(8)));
typedef float v4f __attribute__((ext_vector_type(4)));

// ---------------- prepw + bucket histogram merged (verified R7-R10) ----------------

__global__ __launch_bounds__(NT) void prep_bhist_kernel(const float* __restrict__ W1, const float* __restrict__ W2,
                                                        const float* __restrict__ W3, __half* __restrict__ Wt1,
                                                        __half* __restrict__ Wt2, __half* __restrict__ Wt3,
                                                        __half* __restrict__ bufA, const int* __restrict__ dst,
                                                        int* __restrict__ gbhist, int N, int E, int NBUK) {
    constexpr int TOT = 256 * 128 + 128 * 64 + 64 * 32 + 128;
    for (int i = blockIdx.x * NT + threadIdx.x; i < TOT; i += gridDim.x * NT) {
        if (i < 256 * 128) {
            int k = i >> 7, f = i & 127;
            Wt1[f * 256 + k] = __float2half(W1[i]);
        } else if (i < 256 * 128 + 128 * 64) {
            int j = i - 256 * 128; int k = j >> 6, f = j & 63;
            Wt2[f * 128 + k] = __float2half(W2[j]);
        } else if (i < 256 * 128 + 128 * 64 + 64 * 32) {
            int j = i - 256 * 128 - 128 * 64; int k = j >> 5, f = j & 31;
            Wt3[f * 64 + k] = __float2half(W3[j]);
        } else {
            bufA[(size_t)N * 128 + (i - (256 * 128 + 128 * 64 + 64 * 32))] = __float2half(0.f);
        }
    }
    __shared__ int h[512];
    int tid = threadIdx.x;
    for (int i = tid; i < 512; i += NT) h[i] = 0;
    __syncthreads();
    for (int e = blockIdx.x * NT + tid; e < E; e += gridDim.x * NT)
        atomicAdd(&h[dst[e] >> BSH], 1);
    __syncthreads();
    for (int i = tid; i < NBUK; i += NT)
        if (h[i]) atomicAdd(&gbhist[i], h[i]);
}

// ---------------- bucket scan: bbase[0..NBUK] (exclusive), gcur = bbase ----------------

__global__ __launch_bounds__(NT) void bscan_kernel(const int* __restrict__ gbhist, int* __restrict__ bbase,
                                                   int* __restrict__ gcur, int E, int NBUK) {
    __shared__ int wsum[5];
    int tid = threadIdx.x;
    int lane = tid & 63, wid = tid >> 6;
    int e0 = (2 * tid < NBUK) ? gbhist[2 * tid] : 0;
    int e1 = (2 * tid + 1 < NBUK) ? gbhist[2 * tid + 1] : 0;
    int u = e0 + e1;
    int incl = u;
    #pragma unroll
    for (int off = 1; off < 64; off <<= 1) {
        int t = __shfl_up(incl, off, 64);
        if (lane >= off) incl += t;
    }
    if (lane == 63) wsum[wid] = incl;
    __syncthreads();
    if (tid == 0) { int s = 0; for (int w = 0; w < 4; w++) { int t = wsum[w]; wsum[w] = s; s += t; } }
    __syncthreads();
    int base = wsum[wid] + incl - u;
    if (2 * tid < NBUK)     { bbase[2 * tid] = base;          gcur[2 * tid] = base; }
    if (2 * tid + 1 < NBUK) { bbase[2 * tid + 1] = base + e0; gcur[2 * tid + 1] = base + e0; }
    if (tid == 0) bbase[NBUK] = E;
}

// ---------------- phase 1 body: partition edges into ebuf by bucket (staged, proven) ----------------
// ebuf entry: (dst & 511) << 18 | src   (N < 2^18)

__device__ __forceinline__ void part_body(int bx, const int* __restrict__ src, const int* __restrict__ dst,
                                          int* __restrict__ gcur, int* __restrict__ ebuf,
                                          int E, int NBUK, char* smem) {
    constexpr int EPT = CH / NT;   // 8 edges per thread
    int* hist  = (int*)smem;             // 512
    int* lscan = hist + 512;             // 512
    int* gbase = lscan + 512;            // 512
    int2* stage = (int2*)(gbase + 512);  // CH int2 = 16 KB
    int tid = threadIdx.x;
    int lane = tid & 63;
    int e0 = bx * CH;

    for (int i = tid; i < 512; i += NT) hist[i] = 0;
    __syncthreads();

    int2 ed[EPT]; int rank[EPT]; int buk[EPT];
    #pragma unroll
    for (int j = 0; j < EPT; j++) {
        int e = e0 + j * NT + tid;
        if (e < E) {
            ed[j].x = src[e]; ed[j].y = dst[e];
            buk[j] = ed[j].y >> BSH;
            rank[j] = atomicAdd(&hist[buk[j]], 1);
        } else buk[j] = -1;
    }
    __syncthreads();
    if (tid < 64) {
        int bi = tid * 8;
        int v[8]; int s = 0;
        #pragma unroll
        for (int j = 0; j < 8; j++) { v[j] = s; s += hist[bi + j]; }
        int incl = s;
        #pragma unroll
        for (int off = 1; off < 64; off <<= 1) {
            int t = __shfl_up(incl, off, 64);
            if (lane >= off) incl += t;
        }
        int lb = incl - s;
        #pragma unroll
        for (int j = 0; j < 8; j++) lscan[bi + j] = lb + v[j];
    }
    __syncthreads();
    for (int i = tid; i < NBUK; i += NT) {
        int c = hist[i];
        gbase[i] = c ? atomicAdd(&gcur[i], c) : 0;
    }
    #pragma unroll
    for (int j = 0; j < EPT; j++)
        if (buk[j] >= 0) stage[lscan[buk[j]] + rank[j]] = ed[j];
    __syncthreads();
    int cnt = min(E - e0, CH);
    for (int i = tid; i < cnt; i += NT) {
        int2 e = stage[i];
        int b = e.y >> BSH;
        ebuf[gbase[b] + (i - lscan[b])] = ((e.y & (BNODES - 1)) << 18) | e.x;
    }
}

// ---------------- phase 2 body: per-bucket row_start/pdeg/dis + padded csr fill ----------------

__device__ __forceinline__ void bfill_body(int bx, const int* __restrict__ ebuf, const int* __restrict__ bbase,
                                           int* __restrict__ row_start, int* __restrict__ pdeg,
                                           float* __restrict__ dis, __half* __restrict__ dis_h,
                                           int* __restrict__ csr, int N, char* smem) {
    int* ldeg = (int*)smem;      // 512
    int* lrs  = ldeg + 512;      // 512
    int* wsum = lrs + 512;       // 8
    int tid = threadIdx.x;
    int lane = tid & 63, wid = tid >> 6;
    int b = bx;
    int node0 = b << BSH;
    int nn = min(BNODES, N - node0);
    int beg = bbase[b], end = bbase[b + 1];
    int begp = beg + b * PADCAP;

    for (int i = tid; i < 512; i += NT) ldeg[i] = 0;
    __syncthreads();
    for (int i = beg + tid; i < end; i += NT)
        atomicAdd(&ldeg[ebuf[i] >> 18], 1);
    __syncthreads();
    int e0 = ldeg[2 * tid], e1 = ldeg[2 * tid + 1];
    int p0 = (e0 + 15) & ~15, p1 = (e1 + 15) & ~15;
    int u = p0 + p1;
    int incl = u;
    #pragma unroll
    for (int off = 1; off < 64; off <<= 1) {
        int t = __shfl_up(incl, off, 64);
        if (lane >= off) incl += t;
    }
    if (lane == 63) wsum[wid] = incl;
    __syncthreads();
    if (tid == 0) { int s = 0; for (int w = 0; w < 4; w++) { int t = wsum[w]; wsum[w] = s; s += t; } }
    __syncthreads();
    int base = wsum[wid] + incl - u;
    lrs[2 * tid] = base;
    lrs[2 * tid + 1] = base + p0;
    __syncthreads();
    for (int i = tid; i < nn; i += NT) {
        int dg = ldeg[i];
        pdeg[node0 + i] = (dg + 15) & ~15;
        row_start[node0 + i] = begp + lrs[i];
        float dv = rsqrtf((float)dg + 1.0f);
        dis[node0 + i] = dv;
        dis_h[node0 + i] = __float2half(dv);
    }
    if (bx == 0 && tid == 0) dis_h[N] = __float2half(0.f);
    __syncthreads();
    for (int i = tid; i < 512; i += NT) ldeg[i] = 0;   // reuse as cursor
    __syncthreads();
    for (int i = beg + tid; i < end; i += NT) {
        int code = ebuf[i];
        int l = code >> 18;
        int off = atomicAdd(&ldeg[l], 1);
        csr[begp + lrs[l] + off] = code & 0x3FFFF;
    }
    __syncthreads();
    // pad fill: sentinel N (zero row)
    for (int i = tid; i < nn; i += NT) {
        int dg = ldeg[i];
        int pd = (dg + 15) & ~15;
        int cbase = begp + lrs[i];
        for (int k = dg; k < pd; k++) csr[cbase + k] = N;
    }
}

// ---------------- MFMA GEMM body ----------------
// NORM: computes BN affine from S1/S2/g/bt inline, applies relu(v*a+c) on fp16 load.
// SC:   scales output row by dis[row]. Row N gets zeros (sentinel for padded agg).

template<int K, int F, bool NORM, bool SC>
__device__ __forceinline__ void mgemm_body(int bx, const void* __restrict__ Xv, const __half* __restrict__ Wt,
                                           const float* __restrict__ dis, const float* __restrict__ S1,
                                           const float* __restrict__ S2, const float* __restrict__ g,
                                           const float* __restrict__ bt, __half* __restrict__ out, int N,
                                           char* smem) {
    constexpr int KC = 32;
    constexpr int CG = F / 16;
    constexpr int LDA = KC + 8;
    __half* As = (__half*)smem;                      // 64*LDA
    __half* Bs = (__half*)(smem + 64 * LDA * 2);     // F*LDA
    float* as_ = (float*)(smem + 64 * LDA * 2 + F * LDA * 2);
    float* cs_ = as_ + K;

    int tid = threadIdx.x;
    if constexpr (NORM) {
        float inv = 1.0f / (float)N;
        for (int i = tid; i < K; i += NT) {
            float mu = S1[i] * inv;
            float var = fmaxf(S2[i] * inv - mu * mu, 0.f);
            float av = g[i] * rsqrtf(var + EPS);
            as_[i] = av;
            cs_[i] = bt[i] - mu * av;
        }
        __syncthreads();
    }
    int row0 = bx * 64;
    int wid = tid >> 6, lane = tid & 63;
    int quad = lane >> 4, l16 = lane & 15;
    int tr = tid >> 3;
    int tk = (tid & 7) * 4;

    v4f acc[CG];
    #pragma unroll
    for (int gg = 0; gg < CG; gg++) acc[gg] = (v4f)0.f;

    for (int k0 = 0; k0 < K; k0 += KC) {
        #pragma unroll
        for (int r = tr; r < 64; r += 32) {
            int row = row0 + r;
            __half h0, h1, h2, h3;
            if (row < N) {
                if constexpr (NORM) {
                    const __half2* xp = (const __half2*)((const __half*)Xv + (size_t)row * K + k0 + tk);
                    float2 v0 = __half22float2(xp[0]);
                    float2 v1 = __half22float2(xp[1]);
                    h0 = __float2half(fmaxf(v0.x * as_[k0 + tk]     + cs_[k0 + tk],     0.f));
                    h1 = __float2half(fmaxf(v0.y * as_[k0 + tk + 1] + cs_[k0 + tk + 1], 0.f));
                    h2 = __float2half(fmaxf(v1.x * as_[k0 + tk + 2] + cs_[k0 + tk + 2], 0.f));
                    h3 = __float2half(fmaxf(v1.y * as_[k0 + tk + 3] + cs_[k0 + tk + 3], 0.f));
                } else {
                    float4 v = *(const float4*)((const float*)Xv + (size_t)row * K + k0 + tk);
                    h0 = __float2half(v.x); h1 = __float2half(v.y);
                    h2 = __float2half(v.z); h3 = __float2half(v.w);
                }
            } else {
                h0 = h1 = h2 = h3 = __float2half(0.f);
            }
            __half2* dst = (__half2*)&As[r * LDA + tk];
            dst[0] = __halves2half2(h0, h1);
            dst[1] = __halves2half2(h2, h3);
        }
        #pragma unroll
        for (int n = tr; n < F; n += 32) {
            const __half2* wp = (const __half2*)(Wt + (size_t)n * K + k0 + tk);
            __half2* dst = (__half2*)&Bs[n * LDA + tk];
            dst[0] = wp[0];
            dst[1] = wp[1];
        }
        __syncthreads();
        v8h a = *(const v8h*)&As[(wid * 16 + l16) * LDA + quad * 8];
        #pragma unroll
        for (int gg = 0; gg < CG; gg++) {
            v8h b = *(const v8h*)&Bs[(gg * 16 + l16) * LDA + quad * 8];
            acc[gg] = __builtin_amdgcn_mfma_f32_16x16x32_f16(a, b, acc[gg], 0, 0, 0);
        }
        __syncthreads();
    }
    #pragma unroll
    for (int reg = 0; reg < 4; reg++) {
        int row = row0 + wid * 16 + quad * 4 + reg;
        if (row < N) {
            float d = SC ? dis[row] : 1.0f;
            #pragma unroll
            for (int gg = 0; gg < CG; gg++)
                out[(size_t)row * F + gg * 16 + l16] = __float2half(d * acc[gg][reg]);
        } else if (row == N) {
            #pragma unroll
            for (int gg = 0; gg < CG; gg++)
                out[(size_t)row * F + gg * 16 + l16] = __float2half(0.f);
        }
    }
}

template<int K, int F, bool NORM, bool SC>
__global__ __launch_bounds__(NT) void mgemm_kernel(const void* __restrict__ Xv, const __half* __restrict__ Wt,
                                                   const float* __restrict__ dis, const float* __restrict__ S1,
                                                   const float* __restrict__ S2, const float* __restrict__ g,
                                                   const float* __restrict__ bt, __half* __restrict__ out, int N) {
    constexpr int SMB = 64 * 40 * 2 + F * 40 * 2 + (NORM ? 8 * K : 0);
    __shared__ __align__(16) char smem[SMB];
    mgemm_body<K, F, NORM, SC>(blockIdx.x, Xv, Wt, dis, S1, S2, g, bt, out, N, smem);
}

// ---------------- fat kernels: CSR build || gemm1 ----------------

__global__ __launch_bounds__(NT) void fat1_kernel(const int* __restrict__ src, const int* __restrict__ dst,
                                                  int* __restrict__ gcur, int* __restrict__ ebuf, int E, int NBUK,
                                                  int PB, const float* __restrict__ x, const __half* __restrict__ Wt1,
                                                  __half* __restrict__ bufA, int N) {
    // part: 3*512*4 + CH*8 = 6144 + 16384 = 22528; gemm1: 15360 -> max 22528
    __shared__ __align__(16) char smem[22528];
    if ((int)blockIdx.x < PB)
        part_body(blockIdx.x, src, dst, gcur, ebuf, E, NBUK, smem);
    else
        mgemm_body<256, 128, false, false>((int)blockIdx.x - PB, x, Wt1, nullptr, nullptr, nullptr, nullptr,
                                           nullptr, bufA, N, smem);
}

__global__ __launch_bounds__(NT) void fat2_kernel(const int* __restrict__ ebuf, const int* __restrict__ bbase,
                                                  int* __restrict__ row_start, int* __restrict__ pdeg,
                                                  float* __restrict__ dis, __half* __restrict__ dis_h,
                                                  int* __restrict__ csr, const float* __restrict__ x,
                                                  const __half* __restrict__ Wt1, __half* __restrict__ bufA,
                                                  int N, int NBUK, int A) {
    __shared__ __align__(16) char smem[15872];
    if ((int)blockIdx.x < NBUK)
        bfill_body(blockIdx.x, ebuf, bbase, row_start, pdeg, dis, dis_h, csr, N, smem);
    else
        mgemm_body<256, 128, false, false>((int)blockIdx.x - NBUK + A, x, Wt1, nullptr, nullptr, nullptr, nullptr,
                                           nullptr, bufA, N, smem);
}

// ---------------- aggregation: pre[n] = fp16( dis[n]*(Σ terms) + b ) ----------------
// agg_unit<NB>: gather NB 16-entry csr blocks' rows in one shot (NB*U gathers per lane
// in flight). Per-chain accumulation stays in block order for every nb -> results are
// bit-identical to the R4 ladder regardless of BIGU. BIGU=3 for agg2/agg3 turns the
// nb=3 case (46% of nodes) from two serial latency units into one (latency-bound fix);
// agg1 keeps BIGU=2 (byte-bound at the 3.75 TB/s wall; extra VGPR would cut waves).

template<int NB, int U, int SUBS, int FSH, bool DISW>
__device__ __forceinline__ void agg_unit(const int*& cp, const __half* __restrict__ hd,
                                         const __half* __restrict__ dis_h, int fo,
                                         __half2 (&hacc)[U][4]) {
    int s[NB * U];
    #pragma unroll
    for (int bq = 0; bq < NB; bq++)
        #pragma unroll
        for (int u = 0; u < U; u++) s[bq * U + u] = cp[bq * 16 + u * SUBS];
    cp += NB * 16;
    int4 v[NB * U];
    __half dv[NB * U];
    #pragma unroll
    for (int t = 0; t < NB * U; t++) {
        v[t] = *(const int4*)(hd + (((size_t)s[t] << FSH) + fo));
        if constexpr (DISW) dv[t] = dis_h[s[t]];
    }
    #pragma unroll
    for (int t = 0; t < NB * U; t++) {
        const __half2* hv = (const __half2*)&v[t];
        constexpr int UM = U - 1;
        int u = t & UM;
        if constexpr (DISW) {
            __half2 dd = __half2half2(dv[t]);
            #pragma unroll
            for (int j = 0; j < 4; j++) hacc[u][j] = __hfma2(hv[j], dd, hacc[u][j]);
        } else {
            #pragma unroll
            for (int j = 0; j < 4; j++) hacc[u][j] = __hadd2(hacc[u][j], hv[j]);
        }
    }
}

template<int F, int U, int BIGU, bool DISW>
__global__ __launch_bounds__(NT) void agg_kernel(const __half* __restrict__ hd, const int* __restrict__ csr,
                                                 const int* __restrict__ row_start, const int* __restrict__ pdeg,
                                                 const __half* __restrict__ dis_h, const float* __restrict__ dis,
                                                 const float* __restrict__ b, __half* __restrict__ pre, int N) {
    constexpr int LR = F / 8;      // lanes per row (16 B each)
    constexpr int SUBS = 64 / LR;  // rows gathered per 16-block per wave; SUBS*U == 16
    constexpr int FSH = (F == 128) ? 7 : (F == 64) ? 6 : 5;
    int node = (blockIdx.x * NT + threadIdx.x) >> 6;
    if (node >= N) return;
    int lane = threadIdx.x & 63;
    int fl = lane % LR, sub = lane / LR;
    int beg = row_start[node];
    int nb = pdeg[node] >> 4;      // number of 16-entry blocks
    int fo = fl * 8;

    __half2 hacc[U][4];
    #pragma unroll
    for (int u = 0; u < U; u++)
        #pragma unroll
        for (int j = 0; j < 4; j++) hacc[u][j] = __half2half2(__half(0.f));

    if (sub == 0) {   // self term
        int4 v = *(const int4*)(hd + (((size_t)node << FSH) + fo));
        const __half2* hv = (const __half2*)&v;
        if constexpr (DISW) {
            __half2 dd = __half2half2(dis_h[node]);
            #pragma unroll
            for (int j = 0; j < 4; j++) hacc[0][j] = __hmul2(hv[j], dd);
        } else {
            #pragma unroll
            for (int j = 0; j < 4; j++) hacc[0][j] = hv[j];
        }
    }
    const int* cp = csr + beg + sub;
    int rem = nb;
    while (rem >= BIGU) {
        agg_unit<BIGU, U, SUBS, FSH, DISW>(cp, hd, dis_h, fo, hacc);
        rem -= BIGU;
    }
    if constexpr (BIGU > 2) {
        if (rem == 2)      agg_unit<2, U, SUBS, FSH, DISW>(cp, hd, dis_h, fo, hacc);
        else if (rem == 1) agg_unit<1, U, SUBS, FSH, DISW>(cp, hd, dis_h, fo, hacc);
    } else {
        if (rem == 1)      agg_unit<1, U, SUBS, FSH, DISW>(cp, hd, dis_h, fo, hacc);
    }
    // convert to f32 once, then exact cross-sub reduction
    float acc[8];
    #pragma unroll
    for (int j = 0; j < 4; j++) {
        float2 f = __half22float2(hacc[0][j]);
        acc[2 * j] = f.x; acc[2 * j + 1] = f.y;
    }
    #pragma unroll
    for (int u = 1; u < U; u++)
        #pragma unroll
        for (int j = 0; j < 4; j++) {
            float2 f = __half22float2(hacc[u][j]);
            acc[2 * j] += f.x; acc[2 * j + 1] += f.y;
        }
    #pragma unroll
    for (int m = LR; m < 64; m <<= 1)
        #pragma unroll
        for (int j = 0; j < 8; j++) acc[j] += __shfl_xor(acc[j], m, 64);
    if (sub == 0) {
        float d = dis[node];
        float4 b0 = *(const float4*)(b + fo);
        float4 b1 = *(const float4*)(b + fo + 4);
        __half2 h[4];
        h[0] = __floats2half2_rn(d * acc[0] + b0.x, d * acc[1] + b0.y);
        h[1] = __floats2half2_rn(d * acc[2] + b0.z, d * acc[3] + b0.w);
        h[2] = __floats2half2_rn(d * acc[4] + b1.x, d * acc[5] + b1.y);
        h[3] = __floats2half2_rn(d * acc[6] + b1.z, d * acc[7] + b1.w);
        *(int4*)(pre + (((size_t)node << FSH) + fo)) = *(int4*)h;
    }
}

// ---------------- BN statistics (256-block form: low atomic contention) ----------------

template<int F>
__global__ __launch_bounds__(NT) void stats_kernel(const __half* __restrict__ pre, float* __restrict__ S1,
                                                   float* __restrict__ S2, int N) {
    constexpr int FP = F / 2;
    constexpr int RPB = NT / FP;
    int tid = threadIdx.x;
    int f = tid % FP, r0 = tid / FP;
    float s1x = 0.f, s1y = 0.f, s2x = 0.f, s2y = 0.f;
    const __half2* p2 = (const __half2*)pre;
    for (int node = blockIdx.x * RPB + r0; node < N; node += gridDim.x * RPB) {
        float2 v = __half22float2(p2[(size_t)node * FP + f]);
        s1x += v.x; s1y += v.y; s2x += v.x * v.x; s2y += v.y * v.y;
    }
    __shared__ float l1x[NT], l1y[NT], l2x[NT], l2y[NT];
    l1x[tid] = s1x; l1y[tid] = s1y; l2x[tid] = s2x; l2y[tid] = s2y;
    __syncthreads();
    if (tid < FP) {
        #pragma unroll
        for (int j = 1; j < RPB; j++) {
            s1x += l1x[tid + j * FP]; s1y += l1y[tid + j * FP];
            s2x += l2x[tid + j * FP]; s2y += l2y[tid + j * FP];
        }
        atomicAdd(&S1[2 * tid], s1x); atomicAdd(&S1[2 * tid + 1], s1y);
        atomicAdd(&S2[2 * tid], s2x); atomicAdd(&S2[2 * tid + 1], s2y);
    }
}

// ---------------- final FC (BN3 params computed inline) ----------------

__global__ __launch_bounds__(NT) void fc_kernel(const __half* __restrict__ pre, const float* __restrict__ S1,
                                                const float* __restrict__ S2, const float* __restrict__ g,
                                                const float* __restrict__ bt, const float* __restrict__ wfc,
                                                const float* __restrict__ bfc, float* __restrict__ out, int N) {
    __shared__ float wa[32], wc[32], ww[32];
    int tid = threadIdx.x;
    if (tid < 32) {
        float inv = 1.0f / (float)N;
        float mu = S1[tid] * inv;
        float var = fmaxf(S2[tid] * inv - mu * mu, 0.f);
        float av = g[tid] * rsqrtf(var + EPS);
        wa[tid] = av; wc[tid] = bt[tid] - mu * av; ww[tid] = wfc[tid];
    }
    __syncthreads();
    int n = blockIdx.x * NT + tid;
    if (n >= N) return;
    const __half2* p = (const __half2*)(pre + (size_t)n * 32);
    float acc = bfc[0];
    #pragma unroll
    for (int i = 0; i < 16; i++) {
        float2 v = __half22float2(p[i]);
        int f = i * 2;
        acc += fmaxf(v.x * wa[f] + wc[f], 0.f) * ww[f];
        acc += fmaxf(v.y * wa[f + 1] + wc[f + 1], 0.f) * ww[f + 1];
    }
    out[n] = acc;
}

// ---------------- launch ----------------

extern "C" void kernel_launch(void* const* d_in, const int* in_sizes, int n_in,
                              void* d_out, int out_size, void* d_ws, size_t ws_size,
                              hipStream_t stream) {
    const float* x   = (const float*)d_in[0];
    const int*   ei  = (const int*)d_in[1];
    const float* W1  = (const float*)d_in[2];
    const float* b1  = (const float*)d_in[3];
    const float* g1  = (const float*)d_in[4];
    const float* bt1 = (const float*)d_in[5];
    const float* W2  = (const float*)d_in[6];
    const float* b2  = (const float*)d_in[7];
    const float* g2  = (const float*)d_in[8];
    const float* bt2 = (const float*)d_in[9];
    const float* W3  = (const float*)d_in[10];
    const float* b3  = (const float*)d_in[11];
    const float* g3  = (const float*)d_in[12];
    const float* bt3 = (const float*)d_in[13];
    const float* Wfc = (const float*)d_in[14];
    const float* bfc = (const float*)d_in[15];
    float* out = (float*)d_out;

    int N = in_sizes[0] / 256;
    int E = in_sizes[1] / 2;
    const int* src = ei;
    const int* dst = ei + E;
    int NBUK = (N + BNODES - 1) >> BSH;

    char* ws = (char*)d_ws;
    size_t off = 0;
    auto alloc = [&](size_t bytes) -> char* {
        char* p = ws + off;
        off += (bytes + 255) & ~(size_t)255;
        return p;
    };
    __half* bufA     = (__half*)alloc((size_t)(N + 1) * 128 * 2);   // h / hd (row N = zero sentinel)
    __half* bufB     = (__half*)alloc((size_t)N * 128 * 2);         // pre-BN aggregated
    int*   ebuf      = (int*)alloc((size_t)E * 4);
    int*   csr       = (int*)alloc(((size_t)E + (size_t)NBUK * PADCAP) * 4);
    int*   row_start = (int*)alloc((size_t)N * 4);
    int*   pdeg      = (int*)alloc((size_t)N * 4);
    float* dis       = (float*)alloc((size_t)N * 4);
    __half* dis_h    = (__half*)alloc((size_t)(N + 1) * 2);
    int*   gbhist    = (int*)alloc((size_t)NBUK * 4);
    int*   bbase     = (int*)alloc((size_t)(NBUK + 1) * 4);
    int*   gcur      = (int*)alloc((size_t)NBUK * 4);
    __half* Wt1      = (__half*)alloc(256 * 128 * 2);
    __half* Wt2      = (__half*)alloc(128 * 64 * 2);
    __half* Wt3      = (__half*)alloc(64 * 32 * 2);
    float* stats = (float*)alloc(448 * 4);
    float* S1_1 = stats;       float* S2_1 = S1_1 + 128;
    float* S1_2 = S2_1 + 128;  float* S2_2 = S1_2 + 64;
    float* S1_3 = S2_2 + 64;   float* S2_3 = S1_3 + 32;

    hipMemsetAsync(gbhist, 0, (size_t)NBUK * 4, stream);
    hipMemsetAsync(stats, 0, 448 * 4, stream);

    int GB = (N + 63) / 64;
    int PB = (E + CH - 1) / CH;
    int A = (GB * 3) / 5;           // gemm1 tiles in FAT1; rest in FAT2
    int AB = (N + 3) / 4;           // agg: one wave per node
    int NB = (N + NT - 1) / NT;

    prep_bhist_kernel<<<512, NT, 0, stream>>>(W1, W2, W3, Wt1, Wt2, Wt3, bufA, dst, gbhist, N, E, NBUK);
    bscan_kernel<<<1, NT, 0, stream>>>(gbhist, bbase, gcur, E, NBUK);
    fat1_kernel<<<PB + A, NT, 0, stream>>>(src, dst, gcur, ebuf, E, NBUK, PB, x, Wt1, bufA, N);
    fat2_kernel<<<NBUK + (GB - A), NT, 0, stream>>>(ebuf, bbase, row_start, pdeg, dis, dis_h, csr,
                                                    x, Wt1, bufA, N, NBUK, A);
    // layer 1 (hd unscaled -> DISW agg); BIGU=2 (byte-bound, keep VGPR low)
    agg_kernel<128, 4, 2, true><<<AB, NT, 0, stream>>>(bufA, csr, row_start, pdeg, dis_h, dis, b1, bufB, N);
    stats_kernel<128><<<256, NT, 0, stream>>>(bufB, S1_1, S2_1, N);
    // layer 2; BIGU=3 (latency-bound candidate: 6 gathers in flight for nb>=3 nodes)
    mgemm_kernel<128, 64, true, true><<<GB, NT, 0, stream>>>(bufB, Wt2, dis, S1_1, S2_1, g1, bt1, bufA, N);
    agg_kernel<64, 2, 3, false><<<AB, NT, 0, stream>>>(bufA, csr, row_start, pdeg, dis_h, dis, b2, bufB, N);
    stats_kernel<64><<<256, NT, 0, stream>>>(bufB, S1_2, S2_2, N);
    // layer 3; BIGU=3
    mgemm_kernel<64, 32, true, true><<<GB, NT, 0, stream>>>(bufB, Wt3, dis, S1_2, S2_2, g2, bt2, bufA, N);
    agg_kernel<32, 1, 3, false><<<AB, NT, 0, stream>>>(bufA, csr, row_start, pdeg, dis_h, dis, b3, bufB, N);
    stats_kernel<32><<<256, NT, 0, stream>>>(bufB, S1_3, S2_3, N);
    // head
    fc_kernel<<<NB, NT, 0, stream>>>(bufB, S1_3, S2_3, g3, bt3, Wfc, bfc, out, N);
}